// Round 8
// baseline (351.126 us; speedup 1.0000x reference)
//
#include <hip/hip_runtime.h>

// Problem constants (from reference)
#define B_    256
#define CIN   48
#define CBOT  8
#define H_    4096
#define SCALE_ 0.35355339059327373f   // 1/sqrt(8)

// Evidence so far: 1 block/CU (R6/R7) = 3.2 TB/s effective; 2 blocks/CU
// (R4) = 3.9 TB/s -- independent block populations keep memory queues fed
// (phase drift), per-wave ILP is a null lever (R7). R4's cost was its 2x
// HBM read: sibling blocks (same batch) had adjacent blockIdx -> different
// XCDs -> no L2 reuse. This round pairs siblings on the SAME XCD: linear
// ids (L, L+8) are both == L (mod 8) -> same XCD -> the second read of each
// batch chunk hits that XCD's 4 MB L2 (batch = 786 KB, siblings near-
// lockstep). Gram is summed lo-half-then-hi-half in BOTH siblings ->
// bitwise-identical softmax. NT stores kept from R6. No cross-block state.
#define NT    512
#define HHALF 2048

typedef float vf4 __attribute__((ext_vector_type(4)));

__global__ __launch_bounds__(NT, 4) void ultimus_pair(
    const float* __restrict__ x,        // [B, 48, 4096]
    const float* __restrict__ w_down,   // [8, 48]
    const float* __restrict__ w_up,     // [48, 8]
    float* __restrict__ out)            // [B, 48, 4096] (write-only)
{
    // blockIdx.x = L in [0,512). XCD = L % 8 (round-robin). Pair (L, L+8):
    // same XCD, same batch, halves 0/1.
    const int L = blockIdx.x;
    const int j = L & 15;
    const int b = ((L >> 4) << 3) | (j & 7);   // batch 0..255, twice each
    const int s = j >> 3;                       // half 0/1 (own)
    const int t = threadIdx.x;

    __shared__ float s_wdT[CIN * CBOT]; // w_down transposed: [c][o]
    __shared__ float s_red[8 * 36];     // per-wave gram partials (8 waves)
    __shared__ float s_am [CBOT * CBOT];// softmaxed attention matrix
    __shared__ float s_M  [CIN * CBOT]; // M = w_up @ am, [c][j]

    if (t < CIN * CBOT) {
        const int c = t >> 3, o = t & 7;
        s_wdT[t] = w_down[o * CIN + c];
    }
    __syncthreads();

    const float* xb = x + (size_t)b * (CIN * H_);
    const int hLo = t << 2;             // absolute half-0 columns
    const int hHi = HHALF + (t << 2);   // absolute half-1 columns

    // ---- Phase 1: kqv for BOTH absolute halves ----
    float accLo[CBOT][4], accHi[CBOT][4];
    #pragma unroll
    for (int o = 0; o < CBOT; ++o) {
        accLo[o][0] = accLo[o][1] = accLo[o][2] = accLo[o][3] = 0.0f;
        accHi[o][0] = accHi[o][1] = accHi[o][2] = accHi[o][3] = 0.0f;
    }

    #pragma unroll 4
    for (int c = 0; c < CIN; ++c) {
        const vf4 xvLo = *reinterpret_cast<const vf4*>(xb + (size_t)c * H_ + hLo);
        const vf4 xvHi = *reinterpret_cast<const vf4*>(xb + (size_t)c * H_ + hHi);
        #pragma unroll
        for (int o = 0; o < CBOT; ++o) {
            const float w = s_wdT[c * CBOT + o];
            accLo[o][0] += w * xvLo.x;  accLo[o][1] += w * xvLo.y;
            accLo[o][2] += w * xvLo.z;  accLo[o][3] += w * xvLo.w;
            accHi[o][0] += w * xvHi.x;  accHi[o][1] += w * xvHi.y;
            accHi[o][2] += w * xvHi.z;  accHi[o][3] += w * xvHi.w;
        }
    }

    // ---- Phase 2: FULL gram, lo products first then hi (order fixed so
    //      both siblings produce bitwise-identical sums) ----
    float g[36];
    {
        int idx = 0;
        #pragma unroll
        for (int i = 0; i < CBOT; ++i) {
            #pragma unroll
            for (int jj = i; jj < CBOT; ++jj, ++idx) {
                g[idx] = accLo[i][0] * accLo[jj][0] + accLo[i][1] * accLo[jj][1]
                       + accLo[i][2] * accLo[jj][2] + accLo[i][3] * accLo[jj][3]
                       + accHi[i][0] * accHi[jj][0] + accHi[i][1] * accHi[jj][1]
                       + accHi[i][2] * accHi[jj][2] + accHi[i][3] * accHi[jj][3];
            }
        }
    }
    #pragma unroll
    for (int k = 0; k < 36; ++k) {
        float v = g[k];
        v += __shfl_down(v, 32, 64);
        v += __shfl_down(v, 16, 64);
        v += __shfl_down(v,  8, 64);
        v += __shfl_down(v,  4, 64);
        v += __shfl_down(v,  2, 64);
        v += __shfl_down(v,  1, 64);
        g[k] = v;   // lane 0 holds wave sum
    }
    const int wave = t >> 6;   // 8 waves
    const int lane = t & 63;
    if (lane == 0) {
        #pragma unroll
        for (int k = 0; k < 36; ++k) s_red[wave * 36 + k] = g[k];
    }
    __syncthreads();
    if (t < 36) {
        float v = 0.0f;
        #pragma unroll
        for (int w = 0; w < 8; ++w) v += s_red[w * 36 + t];
        s_red[t] = v;   // slot t: own-index rewrite, no cross-read hazard
    }
    __syncthreads();

    // ---- Phase 3: softmax rows (threads 0..7) ----
    if (t < 8) {
        float row[8];
        #pragma unroll
        for (int jj = 0; jj < 8; ++jj) {
            const int i2 = t < jj ? t : jj;
            const int j2 = t < jj ? jj : t;
            const int tri = i2 * 8 - (i2 * (i2 - 1)) / 2 + (j2 - i2);
            row[jj] = s_red[tri] * SCALE_;
        }
        float m = row[0];
        #pragma unroll
        for (int jj = 1; jj < 8; ++jj) m = fmaxf(m, row[jj]);
        float sum = 0.0f;
        #pragma unroll
        for (int jj = 0; jj < 8; ++jj) { row[jj] = __expf(row[jj] - m); sum += row[jj]; }
        const float inv = 1.0f / sum;
        #pragma unroll
        for (int jj = 0; jj < 8; ++jj) s_am[t * 8 + jj] = row[jj] * inv;
    }
    __syncthreads();

    // M[c][j] = sum_o w_up[c][o] * am[o][j]  (folds both tiny matmuls)
    if (t < CIN * CBOT) {
        const int c = t >> 3, jj = t & 7;
        float v = 0.0f;
        #pragma unroll
        for (int o = 0; o < CBOT; ++o)
            v += w_up[c * CBOT + o] * s_am[o * CBOT + jj];
        s_M[t] = v;
    }
    __syncthreads();

    // ---- Phase 4: select own-half kqv (uniform branch), stream output ----
    float own[CBOT][4];
    if (s == 0) {
        #pragma unroll
        for (int o = 0; o < CBOT; ++o) {
            own[o][0] = accLo[o][0]; own[o][1] = accLo[o][1];
            own[o][2] = accLo[o][2]; own[o][3] = accLo[o][3];
        }
    } else {
        #pragma unroll
        for (int o = 0; o < CBOT; ++o) {
            own[o][0] = accHi[o][0]; own[o][1] = accHi[o][1];
            own[o][2] = accHi[o][2]; own[o][3] = accHi[o][3];
        }
    }

    const int hO = s * HHALF + (t << 2);
    float* ob = out + (size_t)b * (CIN * H_) + hO;
    #pragma unroll 8
    for (int c = 0; c < CIN; ++c) {
        vf4 r;
        r.x = r.y = r.z = r.w = 0.0f;
        #pragma unroll
        for (int jj = 0; jj < CBOT; ++jj) {
            const float mcj = s_M[c * CBOT + jj];
            r.x += mcj * own[jj][0];
            r.y += mcj * own[jj][1];
            r.z += mcj * own[jj][2];
            r.w += mcj * own[jj][3];
        }
        __builtin_nontemporal_store(r, reinterpret_cast<vf4*>(ob + (size_t)c * H_));
    }
}

extern "C" void kernel_launch(void* const* d_in, const int* in_sizes, int n_in,
                              void* d_out, int out_size, void* d_ws, size_t ws_size,
                              hipStream_t stream) {
    const float* x      = (const float*)d_in[0];
    const float* w_down = (const float*)d_in[1];
    const float* w_up   = (const float*)d_in[2];
    float* out          = (float*)d_out;

    hipLaunchKernelGGL(ultimus_pair, dim3(2 * B_), dim3(NT), 0, stream,
                       x, w_down, w_up, out);
}